// Round 1
// baseline (2062.559 us; speedup 1.0000x reference)
//
#include <hip/hip_runtime.h>

#define N_TOTAL   150100
#define NUM_USERS 100000
#define DIM       64
#define NUM_LAYERS 3

// One wave (64 lanes) per batch row: acc[b][:] = node_emb[row][:]
__global__ void gather_init(const float* __restrict__ node_emb,
                            const int* __restrict__ user_ids,
                            const int* __restrict__ item_ids,
                            float* __restrict__ acc, int batch) {
    int t = blockIdx.x * blockDim.x + threadIdx.x;
    int b = t >> 6, lane = t & 63;
    if (b >= 2 * batch) return;
    int row = (b < batch) ? user_ids[b] : (NUM_USERS + item_ids[b - batch]);
    acc[(size_t)b * DIM + lane] = node_emb[(size_t)row * DIM + lane];
}

// One wave per edge: out[row][:] += val * emb[col][:]
__global__ void scatter_edges(const float* __restrict__ emb,
                              const float* __restrict__ val,
                              const int* __restrict__ rows,
                              const int* __restrict__ cols,
                              float* __restrict__ out, int n_edges) {
    int t = blockIdx.x * blockDim.x + threadIdx.x;
    int e = t >> 6, lane = t & 63;
    if (e >= n_edges) return;
    int r = rows[e];
    int c = cols[e];
    float v = val[e];
    float m = v * emb[(size_t)c * DIM + lane];
    atomicAdd(&out[(size_t)r * DIM + lane], m);
}

// acc[b][:] += emb[row_b][:]
__global__ void acc_gather_add(const float* __restrict__ emb,
                               const int* __restrict__ user_ids,
                               const int* __restrict__ item_ids,
                               float* __restrict__ acc, int batch) {
    int t = blockIdx.x * blockDim.x + threadIdx.x;
    int b = t >> 6, lane = t & 63;
    if (b >= 2 * batch) return;
    int row = (b < batch) ? user_ids[b] : (NUM_USERS + item_ids[b - batch]);
    acc[(size_t)b * DIM + lane] += emb[(size_t)row * DIM + lane];
}

// out[b] = dot(acc[b], acc[batch+b]) / 16   (final = acc/4 for both sides)
__global__ void final_dot(const float* __restrict__ acc,
                          float* __restrict__ out, int batch) {
    int t = blockIdx.x * blockDim.x + threadIdx.x;
    int b = t >> 6, lane = t & 63;
    if (b >= batch) return;
    float s = acc[(size_t)b * DIM + lane] * acc[(size_t)(b + batch) * DIM + lane];
    #pragma unroll
    for (int off = 32; off > 0; off >>= 1) s += __shfl_down(s, off, 64);
    if (lane == 0) out[b] = s * (1.0f / 16.0f);
}

extern "C" void kernel_launch(void* const* d_in, const int* in_sizes, int n_in,
                              void* d_out, int out_size, void* d_ws, size_t ws_size,
                              hipStream_t stream) {
    const float* node_emb = (const float*)d_in[0];
    const float* adj_val  = (const float*)d_in[1];
    const int*   adj_row  = (const int*)d_in[2];
    const int*   adj_col  = (const int*)d_in[3];
    const int*   user_ids = (const int*)d_in[4];
    const int*   item_ids = (const int*)d_in[5];
    float* out = (float*)d_out;

    const int n_edges = in_sizes[1];
    const int batch   = in_sizes[4];

    const size_t emb_bytes = (size_t)N_TOTAL * DIM * sizeof(float);
    float* bufA = (float*)d_ws;
    float* bufB = (float*)((char*)d_ws + emb_bytes);
    float* acc  = (float*)((char*)d_ws + 2 * emb_bytes);  // (2*batch, DIM)

    // acc <- node_emb rows at user/item indices (layer-0 contribution)
    {
        int threads = 2 * batch * 64;
        gather_init<<<(threads + 255) / 256, 256, 0, stream>>>(
            node_emb, user_ids, item_ids, acc, batch);
    }

    const float* cur = node_emb;
    float* nxt = bufA;
    for (int l = 0; l < NUM_LAYERS; ++l) {
        hipMemsetAsync(nxt, 0, emb_bytes, stream);
        {
            long long threads = (long long)n_edges * 64;
            int blocks = (int)((threads + 255) / 256);
            scatter_edges<<<blocks, 256, 0, stream>>>(
                cur, adj_val, adj_row, adj_col, nxt, n_edges);
        }
        {
            int threads = 2 * batch * 64;
            acc_gather_add<<<(threads + 255) / 256, 256, 0, stream>>>(
                nxt, user_ids, item_ids, acc, batch);
        }
        cur = nxt;
        nxt = (nxt == bufA) ? bufB : bufA;
    }

    {
        int threads = batch * 64;
        final_dot<<<(threads + 255) / 256, 256, 0, stream>>>(acc, out, batch);
    }
}

// Round 2
// 1269.102 us; speedup vs baseline: 1.6252x; 1.6252x over previous
//
#include <hip/hip_runtime.h>

#define N_TOTAL    150100
#define NUM_USERS  100000
#define DIM        64
#define SCAN_THREADS 1024

// ---------- CSR build ----------

// counts[row[e]]++ for every edge (counts pre-zeroed via memsetAsync)
__global__ void count_rows(const int* __restrict__ rows, int* __restrict__ counts,
                           int n_edges) {
    int e = blockIdx.x * blockDim.x + threadIdx.x;
    if (e >= n_edges) return;
    atomicAdd(&counts[rows[e]], 1);
}

// Single-block exclusive scan over counts[N_TOTAL].
// Writes row_start[0..N_TOTAL] and re-initializes counts[] as the fill cursor.
__global__ void scan_counts(int* __restrict__ counts, int* __restrict__ row_start) {
    __shared__ int sums[SCAN_THREADS];
    const int tid = threadIdx.x;
    const int chunk = (N_TOTAL + SCAN_THREADS - 1) / SCAN_THREADS;  // 147
    const int begin = tid * chunk;
    const int end = (begin + chunk < N_TOTAL) ? (begin + chunk) : N_TOTAL;

    int s = 0;
    for (int i = begin; i < end; ++i) s += counts[i];
    sums[tid] = s;
    __syncthreads();

    // Hillis–Steele inclusive scan in LDS
    for (int off = 1; off < SCAN_THREADS; off <<= 1) {
        int v = 0;
        if (tid >= off) v = sums[tid - off];
        __syncthreads();
        if (tid >= off) sums[tid] += v;
        __syncthreads();
    }

    int run = (tid == 0) ? 0 : sums[tid - 1];
    for (int i = begin; i < end; ++i) {
        int c = counts[i];
        row_start[i] = run;
        counts[i] = run;   // cursor init (destroys count, row_start keeps it)
        run += c;
    }
    if (tid == SCAN_THREADS - 1) row_start[N_TOTAL] = run;
}

// Scatter edges into CSR slots: idx = cursor[row]++; col_p[idx]=col; val_p[idx]=val
__global__ void fill_csr(const int* __restrict__ rows, const int* __restrict__ cols,
                         const float* __restrict__ vals, int* __restrict__ cursor,
                         int* __restrict__ col_p, float* __restrict__ val_p,
                         int n_edges) {
    int e = blockIdx.x * blockDim.x + threadIdx.x;
    if (e >= n_edges) return;
    int r = rows[e];
    int idx = atomicAdd(&cursor[r], 1);
    col_p[idx] = cols[e];
    val_p[idx] = vals[e];
}

// ---------- propagation ----------

// One wave per destination row: out[r][:] = sum_k val_p[k] * emb[col_p[k]][:]
__global__ void spmm_csr(const float* __restrict__ emb,
                         const int* __restrict__ row_start,
                         const int* __restrict__ col_p,
                         const float* __restrict__ val_p,
                         float* __restrict__ out) {
    int t = blockIdx.x * blockDim.x + threadIdx.x;
    int r = t >> 6, lane = t & 63;
    if (r >= N_TOTAL) return;
    int k0 = row_start[r], k1 = row_start[r + 1];
    float s = 0.0f;
    int k = k0;
    if (k < k1) {
        int c = col_p[k];
        float v = val_p[k];
        for (++k; k < k1; ++k) {
            int cn = col_p[k];
            float vn = val_p[k];
            s += v * emb[(size_t)c * DIM + lane];
            c = cn; v = vn;
        }
        s += v * emb[(size_t)c * DIM + lane];
    }
    out[(size_t)r * DIM + lane] = s;
}

// Layer-3 shortcut: CSR row-sum only at the 2*batch gathered rows, += into acc
__global__ void spmm_rows_acc(const float* __restrict__ emb,
                              const int* __restrict__ row_start,
                              const int* __restrict__ col_p,
                              const float* __restrict__ val_p,
                              const int* __restrict__ user_ids,
                              const int* __restrict__ item_ids,
                              float* __restrict__ acc, int batch) {
    int t = blockIdx.x * blockDim.x + threadIdx.x;
    int b = t >> 6, lane = t & 63;
    if (b >= 2 * batch) return;
    int r = (b < batch) ? user_ids[b] : (NUM_USERS + item_ids[b - batch]);
    int k0 = row_start[r], k1 = row_start[r + 1];
    float s = 0.0f;
    for (int k = k0; k < k1; ++k) {
        s += val_p[k] * emb[(size_t)col_p[k] * DIM + lane];
    }
    acc[(size_t)b * DIM + lane] += s;
}

// ---------- readout ----------

__global__ void gather_init(const float* __restrict__ node_emb,
                            const int* __restrict__ user_ids,
                            const int* __restrict__ item_ids,
                            float* __restrict__ acc, int batch) {
    int t = blockIdx.x * blockDim.x + threadIdx.x;
    int b = t >> 6, lane = t & 63;
    if (b >= 2 * batch) return;
    int row = (b < batch) ? user_ids[b] : (NUM_USERS + item_ids[b - batch]);
    acc[(size_t)b * DIM + lane] = node_emb[(size_t)row * DIM + lane];
}

__global__ void acc_gather_add(const float* __restrict__ emb,
                               const int* __restrict__ user_ids,
                               const int* __restrict__ item_ids,
                               float* __restrict__ acc, int batch) {
    int t = blockIdx.x * blockDim.x + threadIdx.x;
    int b = t >> 6, lane = t & 63;
    if (b >= 2 * batch) return;
    int row = (b < batch) ? user_ids[b] : (NUM_USERS + item_ids[b - batch]);
    acc[(size_t)b * DIM + lane] += emb[(size_t)row * DIM + lane];
}

__global__ void final_dot(const float* __restrict__ acc,
                          float* __restrict__ out, int batch) {
    int t = blockIdx.x * blockDim.x + threadIdx.x;
    int b = t >> 6, lane = t & 63;
    if (b >= batch) return;
    float s = acc[(size_t)b * DIM + lane] * acc[(size_t)(b + batch) * DIM + lane];
    #pragma unroll
    for (int off = 32; off > 0; off >>= 1) s += __shfl_down(s, off, 64);
    if (lane == 0) out[b] = s * (1.0f / 16.0f);
}

// ---------- launch ----------

static inline size_t align256(size_t x) { return (x + 255) & ~(size_t)255; }

extern "C" void kernel_launch(void* const* d_in, const int* in_sizes, int n_in,
                              void* d_out, int out_size, void* d_ws, size_t ws_size,
                              hipStream_t stream) {
    const float* node_emb = (const float*)d_in[0];
    const float* adj_val  = (const float*)d_in[1];
    const int*   adj_row  = (const int*)d_in[2];
    const int*   adj_col  = (const int*)d_in[3];
    const int*   user_ids = (const int*)d_in[4];
    const int*   item_ids = (const int*)d_in[5];
    float* out = (float*)d_out;

    const int n_edges = in_sizes[1];
    const int batch   = in_sizes[4];

    const size_t emb_bytes = (size_t)N_TOTAL * DIM * sizeof(float);

    char* p = (char*)d_ws;
    size_t off = 0;
    float* bufA = (float*)(p + off); off = align256(off + emb_bytes);
    float* bufB = (float*)(p + off); off = align256(off + emb_bytes);
    float* acc  = (float*)(p + off); off = align256(off + (size_t)2 * batch * DIM * sizeof(float));
    int* row_start = (int*)(p + off); off = align256(off + (size_t)(N_TOTAL + 1) * sizeof(int));
    int* cursor    = (int*)(p + off); off = align256(off + (size_t)N_TOTAL * sizeof(int));
    int* col_p     = (int*)(p + off); off = align256(off + (size_t)n_edges * sizeof(int));
    float* val_p   = (float*)(p + off); off = align256(off + (size_t)n_edges * sizeof(float));
    (void)ws_size;

    const int eblocks = (n_edges + 255) / 256;

    // --- CSR build ---
    hipMemsetAsync(cursor, 0, (size_t)N_TOTAL * sizeof(int), stream);
    count_rows<<<eblocks, 256, 0, stream>>>(adj_row, cursor, n_edges);
    scan_counts<<<1, SCAN_THREADS, 0, stream>>>(cursor, row_start);
    fill_csr<<<eblocks, 256, 0, stream>>>(adj_row, adj_col, adj_val, cursor,
                                          col_p, val_p, n_edges);

    // --- acc init (layer-0) ---
    {
        int threads = 2 * batch * 64;
        gather_init<<<(threads + 255) / 256, 256, 0, stream>>>(
            node_emb, user_ids, item_ids, acc, batch);
    }

    const int rblocks = (N_TOTAL * 64 + 255) / 256;
    const int gblocks = (2 * batch * 64 + 255) / 256;

    // layer 1: full
    spmm_csr<<<rblocks, 256, 0, stream>>>(node_emb, row_start, col_p, val_p, bufA);
    acc_gather_add<<<gblocks, 256, 0, stream>>>(bufA, user_ids, item_ids, acc, batch);

    // layer 2: full
    spmm_csr<<<rblocks, 256, 0, stream>>>(bufA, row_start, col_p, val_p, bufB);
    acc_gather_add<<<gblocks, 256, 0, stream>>>(bufB, user_ids, item_ids, acc, batch);

    // layer 3: only the 2*batch rows we actually read
    spmm_rows_acc<<<gblocks, 256, 0, stream>>>(bufB, row_start, col_p, val_p,
                                               user_ids, item_ids, acc, batch);

    // readout
    {
        int threads = batch * 64;
        final_dot<<<(threads + 255) / 256, 256, 0, stream>>>(acc, out, batch);
    }
}

// Round 3
// 825.245 us; speedup vs baseline: 2.4993x; 1.5378x over previous
//
#include <hip/hip_runtime.h>

#define N_TOTAL    150100
#define NUM_USERS  100000
#define DIM        64

// hierarchical scan config
#define SCAN_TPB   256
#define SCAN_EPT   8
#define SCAN_EPB   (SCAN_TPB * SCAN_EPT)                 // 2048
#define SCAN_NB    ((N_TOTAL + SCAN_EPB - 1) / SCAN_EPB) // 74  (must be <= 128)

// ---------- CSR build ----------

__global__ void count_rows(const int* __restrict__ rows, int* __restrict__ counts,
                           int n_edges) {
    int e = blockIdx.x * blockDim.x + threadIdx.x;
    if (e >= n_edges) return;
    atomicAdd(&counts[rows[e]], 1);
}

// Stage A: per-block sum of 2048 counts
__global__ void scan_block_sums(const int* __restrict__ counts,
                                int* __restrict__ partial) {
    __shared__ int red[SCAN_TPB / 64];
    int tid = threadIdx.x;
    int base = blockIdx.x * SCAN_EPB + tid * SCAN_EPT;
    int s = 0;
    #pragma unroll
    for (int j = 0; j < SCAN_EPT; ++j) {
        int i = base + j;
        if (i < N_TOTAL) s += counts[i];
    }
    // wave reduce
    #pragma unroll
    for (int off = 32; off > 0; off >>= 1) s += __shfl_down(s, off, 64);
    if ((tid & 63) == 0) red[tid >> 6] = s;
    __syncthreads();
    if (tid == 0) {
        int t = 0;
        #pragma unroll
        for (int w = 0; w < SCAN_TPB / 64; ++w) t += red[w];
        partial[blockIdx.x] = t;
    }
}

// Stage B: single small block exclusive-scans the partials (SCAN_NB <= 128)
__global__ void scan_partials(int* __restrict__ partial, int* __restrict__ row_start) {
    __shared__ int sums[128];
    int tid = threadIdx.x;
    int v = (tid < SCAN_NB) ? partial[tid] : 0;
    sums[tid] = v;
    __syncthreads();
    #pragma unroll
    for (int off = 1; off < 128; off <<= 1) {
        int x = 0;
        if (tid >= off) x = sums[tid - off];
        __syncthreads();
        if (tid >= off) sums[tid] += x;
        __syncthreads();
    }
    if (tid < SCAN_NB) partial[tid] = sums[tid] - v;   // exclusive
    if (tid == 127) row_start[N_TOTAL] = sums[127];    // total = n_edges
}

// Stage C: per-block rescan, write row_start[] and cursor[] (= exclusive prefix)
__global__ void scan_write(int* __restrict__ counts,         // in: counts, out: cursor
                           const int* __restrict__ partial,
                           int* __restrict__ row_start) {
    __shared__ int sums[SCAN_TPB];
    int tid = threadIdx.x;
    int base = blockIdx.x * SCAN_EPB + tid * SCAN_EPT;

    int c[SCAN_EPT];
    int tsum = 0;
    #pragma unroll
    for (int j = 0; j < SCAN_EPT; ++j) {
        int i = base + j;
        c[j] = (i < N_TOTAL) ? counts[i] : 0;
        tsum += c[j];
    }
    sums[tid] = tsum;
    __syncthreads();
    #pragma unroll
    for (int off = 1; off < SCAN_TPB; off <<= 1) {
        int x = 0;
        if (tid >= off) x = sums[tid - off];
        __syncthreads();
        if (tid >= off) sums[tid] += x;
        __syncthreads();
    }
    int run = partial[blockIdx.x] + sums[tid] - tsum;  // exclusive prefix at base
    #pragma unroll
    for (int j = 0; j < SCAN_EPT; ++j) {
        int i = base + j;
        if (i < N_TOTAL) {
            row_start[i] = run;
            counts[i] = run;   // cursor init
            run += c[j];
        }
    }
}

__global__ void fill_csr(const int* __restrict__ rows, const int* __restrict__ cols,
                         const float* __restrict__ vals, int* __restrict__ cursor,
                         int* __restrict__ col_p, float* __restrict__ val_p,
                         int n_edges) {
    int e = blockIdx.x * blockDim.x + threadIdx.x;
    if (e >= n_edges) return;
    int r = rows[e];
    int idx = atomicAdd(&cursor[r], 1);
    col_p[idx] = cols[e];
    val_p[idx] = vals[e];
}

// ---------- propagation ----------

// One wave per destination row; lane-cooperative (col,val) fetch + shfl broadcast.
__global__ void spmm_csr(const float* __restrict__ emb,
                         const int* __restrict__ row_start,
                         const int* __restrict__ col_p,
                         const float* __restrict__ val_p,
                         float* __restrict__ out) {
    int t = blockIdx.x * blockDim.x + threadIdx.x;
    int r = t >> 6, lane = t & 63;
    if (r >= N_TOTAL) return;
    int k0 = row_start[r], k1 = row_start[r + 1];
    float s = 0.0f;
    for (int kb = k0; kb < k1; kb += 64) {
        int cnt = k1 - kb; if (cnt > 64) cnt = 64;
        int   cL = (lane < cnt) ? col_p[kb + lane] : 0;
        float vL = (lane < cnt) ? val_p[kb + lane] : 0.0f;
        for (int j = 0; j < cnt; ++j) {
            int   cj = __shfl(cL, j, 64);
            float vj = __shfl(vL, j, 64);
            s += vj * emb[(size_t)cj * DIM + lane];
        }
    }
    out[(size_t)r * DIM + lane] = s;
}

// Layer-3 shortcut: row-sum only at the 2*batch gathered rows, += into acc
__global__ void spmm_rows_acc(const float* __restrict__ emb,
                              const int* __restrict__ row_start,
                              const int* __restrict__ col_p,
                              const float* __restrict__ val_p,
                              const int* __restrict__ user_ids,
                              const int* __restrict__ item_ids,
                              float* __restrict__ acc, int batch) {
    int t = blockIdx.x * blockDim.x + threadIdx.x;
    int b = t >> 6, lane = t & 63;
    if (b >= 2 * batch) return;
    int r = (b < batch) ? user_ids[b] : (NUM_USERS + item_ids[b - batch]);
    int k0 = row_start[r], k1 = row_start[r + 1];
    float s = 0.0f;
    for (int kb = k0; kb < k1; kb += 64) {
        int cnt = k1 - kb; if (cnt > 64) cnt = 64;
        int   cL = (lane < cnt) ? col_p[kb + lane] : 0;
        float vL = (lane < cnt) ? val_p[kb + lane] : 0.0f;
        for (int j = 0; j < cnt; ++j) {
            int   cj = __shfl(cL, j, 64);
            float vj = __shfl(vL, j, 64);
            s += vj * emb[(size_t)cj * DIM + lane];
        }
    }
    acc[(size_t)b * DIM + lane] += s;
}

// ---------- readout ----------

__global__ void gather_init(const float* __restrict__ node_emb,
                            const int* __restrict__ user_ids,
                            const int* __restrict__ item_ids,
                            float* __restrict__ acc, int batch) {
    int t = blockIdx.x * blockDim.x + threadIdx.x;
    int b = t >> 6, lane = t & 63;
    if (b >= 2 * batch) return;
    int row = (b < batch) ? user_ids[b] : (NUM_USERS + item_ids[b - batch]);
    acc[(size_t)b * DIM + lane] = node_emb[(size_t)row * DIM + lane];
}

__global__ void acc_gather_add(const float* __restrict__ emb,
                               const int* __restrict__ user_ids,
                               const int* __restrict__ item_ids,
                               float* __restrict__ acc, int batch) {
    int t = blockIdx.x * blockDim.x + threadIdx.x;
    int b = t >> 6, lane = t & 63;
    if (b >= 2 * batch) return;
    int row = (b < batch) ? user_ids[b] : (NUM_USERS + item_ids[b - batch]);
    acc[(size_t)b * DIM + lane] += emb[(size_t)row * DIM + lane];
}

__global__ void final_dot(const float* __restrict__ acc,
                          float* __restrict__ out, int batch) {
    int t = blockIdx.x * blockDim.x + threadIdx.x;
    int b = t >> 6, lane = t & 63;
    if (b >= batch) return;
    float s = acc[(size_t)b * DIM + lane] * acc[(size_t)(b + batch) * DIM + lane];
    #pragma unroll
    for (int off = 32; off > 0; off >>= 1) s += __shfl_down(s, off, 64);
    if (lane == 0) out[b] = s * (1.0f / 16.0f);
}

// ---------- launch ----------

static inline size_t align256(size_t x) { return (x + 255) & ~(size_t)255; }

extern "C" void kernel_launch(void* const* d_in, const int* in_sizes, int n_in,
                              void* d_out, int out_size, void* d_ws, size_t ws_size,
                              hipStream_t stream) {
    const float* node_emb = (const float*)d_in[0];
    const float* adj_val  = (const float*)d_in[1];
    const int*   adj_row  = (const int*)d_in[2];
    const int*   adj_col  = (const int*)d_in[3];
    const int*   user_ids = (const int*)d_in[4];
    const int*   item_ids = (const int*)d_in[5];
    float* out = (float*)d_out;

    const int n_edges = in_sizes[1];
    const int batch   = in_sizes[4];

    const size_t emb_bytes = (size_t)N_TOTAL * DIM * sizeof(float);

    char* p = (char*)d_ws;
    size_t off = 0;
    float* bufA = (float*)(p + off); off = align256(off + emb_bytes);
    float* bufB = (float*)(p + off); off = align256(off + emb_bytes);
    float* acc  = (float*)(p + off); off = align256(off + (size_t)2 * batch * DIM * sizeof(float));
    int* row_start = (int*)(p + off); off = align256(off + (size_t)(N_TOTAL + 1) * sizeof(int));
    int* cursor    = (int*)(p + off); off = align256(off + (size_t)N_TOTAL * sizeof(int));
    int* partial   = (int*)(p + off); off = align256(off + (size_t)SCAN_NB * sizeof(int));
    int* col_p     = (int*)(p + off); off = align256(off + (size_t)n_edges * sizeof(int));
    float* val_p   = (float*)(p + off); off = align256(off + (size_t)n_edges * sizeof(float));
    (void)ws_size;

    const int eblocks = (n_edges + 255) / 256;

    // --- CSR build ---
    hipMemsetAsync(cursor, 0, (size_t)N_TOTAL * sizeof(int), stream);
    count_rows<<<eblocks, 256, 0, stream>>>(adj_row, cursor, n_edges);
    scan_block_sums<<<SCAN_NB, SCAN_TPB, 0, stream>>>(cursor, partial);
    scan_partials<<<1, 128, 0, stream>>>(partial, row_start);
    scan_write<<<SCAN_NB, SCAN_TPB, 0, stream>>>(cursor, partial, row_start);
    fill_csr<<<eblocks, 256, 0, stream>>>(adj_row, adj_col, adj_val, cursor,
                                          col_p, val_p, n_edges);

    // --- acc init (layer-0) ---
    {
        int threads = 2 * batch * 64;
        gather_init<<<(threads + 255) / 256, 256, 0, stream>>>(
            node_emb, user_ids, item_ids, acc, batch);
    }

    const int rblocks = (N_TOTAL * 64 + 255) / 256;
    const int gblocks = (2 * batch * 64 + 255) / 256;

    // layer 1: full
    spmm_csr<<<rblocks, 256, 0, stream>>>(node_emb, row_start, col_p, val_p, bufA);
    acc_gather_add<<<gblocks, 256, 0, stream>>>(bufA, user_ids, item_ids, acc, batch);

    // layer 2: full
    spmm_csr<<<rblocks, 256, 0, stream>>>(bufA, row_start, col_p, val_p, bufB);
    acc_gather_add<<<gblocks, 256, 0, stream>>>(bufB, user_ids, item_ids, acc, batch);

    // layer 3: only the 2*batch rows we actually read
    spmm_rows_acc<<<gblocks, 256, 0, stream>>>(bufB, row_start, col_p, val_p,
                                               user_ids, item_ids, acc, batch);

    // readout
    {
        int threads = batch * 64;
        final_dot<<<(threads + 255) / 256, 256, 0, stream>>>(acc, out, batch);
    }
}

// Round 4
// 693.834 us; speedup vs baseline: 2.9727x; 1.1894x over previous
//
#include <hip/hip_runtime.h>

#define N_TOTAL    150100
#define NUM_USERS  100000
#define DIM        64

// hierarchical scan config
#define SCAN_TPB   256
#define SCAN_EPT   8
#define SCAN_EPB   (SCAN_TPB * SCAN_EPT)                 // 2048
#define SCAN_NB    ((N_TOTAL + SCAN_EPB - 1) / SCAN_EPB) // 74  (must be <= 128)

// ---------- CSR build ----------

__global__ void count_rows(const int* __restrict__ rows, int* __restrict__ counts,
                           int n_edges) {
    int e = blockIdx.x * blockDim.x + threadIdx.x;
    if (e >= n_edges) return;
    atomicAdd(&counts[rows[e]], 1);
}

// Stage A: per-block sum of 2048 counts
__global__ void scan_block_sums(const int* __restrict__ counts,
                                int* __restrict__ partial) {
    __shared__ int red[SCAN_TPB / 64];
    int tid = threadIdx.x;
    int base = blockIdx.x * SCAN_EPB + tid * SCAN_EPT;
    int s = 0;
    #pragma unroll
    for (int j = 0; j < SCAN_EPT; ++j) {
        int i = base + j;
        if (i < N_TOTAL) s += counts[i];
    }
    #pragma unroll
    for (int off = 32; off > 0; off >>= 1) s += __shfl_down(s, off, 64);
    if ((tid & 63) == 0) red[tid >> 6] = s;
    __syncthreads();
    if (tid == 0) {
        int t = 0;
        #pragma unroll
        for (int w = 0; w < SCAN_TPB / 64; ++w) t += red[w];
        partial[blockIdx.x] = t;
    }
}

// Stage B: single small block exclusive-scans the partials (SCAN_NB <= 128)
__global__ void scan_partials(int* __restrict__ partial, int* __restrict__ row_start) {
    __shared__ int sums[128];
    int tid = threadIdx.x;
    int v = (tid < SCAN_NB) ? partial[tid] : 0;
    sums[tid] = v;
    __syncthreads();
    #pragma unroll
    for (int off = 1; off < 128; off <<= 1) {
        int x = 0;
        if (tid >= off) x = sums[tid - off];
        __syncthreads();
        if (tid >= off) sums[tid] += x;
        __syncthreads();
    }
    if (tid < SCAN_NB) partial[tid] = sums[tid] - v;   // exclusive
    if (tid == 127) row_start[N_TOTAL] = sums[127];    // total = n_edges
}

// Stage C: per-block rescan, write row_start[] and cursor[] (= exclusive prefix)
__global__ void scan_write(int* __restrict__ counts,         // in: counts, out: cursor
                           const int* __restrict__ partial,
                           int* __restrict__ row_start) {
    __shared__ int sums[SCAN_TPB];
    int tid = threadIdx.x;
    int base = blockIdx.x * SCAN_EPB + tid * SCAN_EPT;

    int c[SCAN_EPT];
    int tsum = 0;
    #pragma unroll
    for (int j = 0; j < SCAN_EPT; ++j) {
        int i = base + j;
        c[j] = (i < N_TOTAL) ? counts[i] : 0;
        tsum += c[j];
    }
    sums[tid] = tsum;
    __syncthreads();
    #pragma unroll
    for (int off = 1; off < SCAN_TPB; off <<= 1) {
        int x = 0;
        if (tid >= off) x = sums[tid - off];
        __syncthreads();
        if (tid >= off) sums[tid] += x;
        __syncthreads();
    }
    int run = partial[blockIdx.x] + sums[tid] - tsum;
    #pragma unroll
    for (int j = 0; j < SCAN_EPT; ++j) {
        int i = base + j;
        if (i < N_TOTAL) {
            row_start[i] = run;
            counts[i] = run;   // cursor init
            run += c[j];
        }
    }
}

// Packed fill: one 8B store per edge {col, val_bits}
__global__ void fill_csr(const int* __restrict__ rows, const int* __restrict__ cols,
                         const float* __restrict__ vals, int* __restrict__ cursor,
                         int2* __restrict__ pair, int n_edges) {
    int e = blockIdx.x * blockDim.x + threadIdx.x;
    if (e >= n_edges) return;
    int r = rows[e];
    int idx = atomicAdd(&cursor[r], 1);
    pair[idx] = make_int2(cols[e], __float_as_int(vals[e]));
}

// ---------- propagation ----------

// 16 lanes per destination row, float4 per lane.
__global__ void spmm_csr(const float4* __restrict__ emb4,
                         const int* __restrict__ row_start,
                         const int2* __restrict__ pair,
                         float4* __restrict__ out4) {
    int t = blockIdx.x * blockDim.x + threadIdx.x;
    int r = t >> 4;
    int sl = t & 15;
    int lane = threadIdx.x & 63;
    int subbase = lane & 48;   // first lane of this 16-lane subgroup
    if (r >= N_TOTAL) return;
    int k0 = row_start[r], k1 = row_start[r + 1];
    float4 s = make_float4(0.f, 0.f, 0.f, 0.f);
    for (int kb = k0; kb < k1; kb += 16) {
        int cnt = k1 - kb; if (cnt > 16) cnt = 16;
        int2 pr = (sl < cnt) ? pair[kb + sl] : make_int2(0, 0);
        for (int j = 0; j < cnt; ++j) {
            int   c = __shfl(pr.x, subbase + j, 64);
            float v = __int_as_float(__shfl(pr.y, subbase + j, 64));
            float4 e = emb4[(size_t)c * (DIM / 4) + sl];
            s.x += v * e.x; s.y += v * e.y; s.z += v * e.z; s.w += v * e.w;
        }
    }
    out4[(size_t)r * (DIM / 4) + sl] = s;
}

// Layer-3 shortcut: row-sum only at the 2*batch gathered rows, += into acc
__global__ void spmm_rows_acc(const float4* __restrict__ emb4,
                              const int* __restrict__ row_start,
                              const int2* __restrict__ pair,
                              const int* __restrict__ user_ids,
                              const int* __restrict__ item_ids,
                              float4* __restrict__ acc4, int batch) {
    int t = blockIdx.x * blockDim.x + threadIdx.x;
    int b = t >> 4;
    int sl = t & 15;
    int lane = threadIdx.x & 63;
    int subbase = lane & 48;
    if (b >= 2 * batch) return;
    int r = (b < batch) ? user_ids[b] : (NUM_USERS + item_ids[b - batch]);
    int k0 = row_start[r], k1 = row_start[r + 1];
    float4 s = make_float4(0.f, 0.f, 0.f, 0.f);
    for (int kb = k0; kb < k1; kb += 16) {
        int cnt = k1 - kb; if (cnt > 16) cnt = 16;
        int2 pr = (sl < cnt) ? pair[kb + sl] : make_int2(0, 0);
        for (int j = 0; j < cnt; ++j) {
            int   c = __shfl(pr.x, subbase + j, 64);
            float v = __int_as_float(__shfl(pr.y, subbase + j, 64));
            float4 e = emb4[(size_t)c * (DIM / 4) + sl];
            s.x += v * e.x; s.y += v * e.y; s.z += v * e.z; s.w += v * e.w;
        }
    }
    float4 a = acc4[(size_t)b * (DIM / 4) + sl];
    a.x += s.x; a.y += s.y; a.z += s.z; a.w += s.w;
    acc4[(size_t)b * (DIM / 4) + sl] = a;
}

// ---------- readout ----------

__global__ void gather_init(const float4* __restrict__ emb4,
                            const int* __restrict__ user_ids,
                            const int* __restrict__ item_ids,
                            float4* __restrict__ acc4, int batch) {
    int t = blockIdx.x * blockDim.x + threadIdx.x;
    int b = t >> 4, sl = t & 15;
    if (b >= 2 * batch) return;
    int row = (b < batch) ? user_ids[b] : (NUM_USERS + item_ids[b - batch]);
    acc4[(size_t)b * (DIM / 4) + sl] = emb4[(size_t)row * (DIM / 4) + sl];
}

__global__ void acc_gather_add(const float4* __restrict__ emb4,
                               const int* __restrict__ user_ids,
                               const int* __restrict__ item_ids,
                               float4* __restrict__ acc4, int batch) {
    int t = blockIdx.x * blockDim.x + threadIdx.x;
    int b = t >> 4, sl = t & 15;
    if (b >= 2 * batch) return;
    int row = (b < batch) ? user_ids[b] : (NUM_USERS + item_ids[b - batch]);
    float4 a = acc4[(size_t)b * (DIM / 4) + sl];
    float4 e = emb4[(size_t)row * (DIM / 4) + sl];
    a.x += e.x; a.y += e.y; a.z += e.z; a.w += e.w;
    acc4[(size_t)b * (DIM / 4) + sl] = a;
}

__global__ void final_dot(const float4* __restrict__ acc4,
                          float* __restrict__ out, int batch) {
    int t = blockIdx.x * blockDim.x + threadIdx.x;
    int b = t >> 4, sl = t & 15;
    if (b >= batch) return;
    float4 u = acc4[(size_t)b * (DIM / 4) + sl];
    float4 v = acc4[(size_t)(b + batch) * (DIM / 4) + sl];
    float s = u.x * v.x + u.y * v.y + u.z * v.z + u.w * v.w;
    #pragma unroll
    for (int off = 8; off > 0; off >>= 1) s += __shfl_down(s, off, 64);
    if (sl == 0) out[b] = s * (1.0f / 16.0f);
}

// ---------- launch ----------

static inline size_t align256(size_t x) { return (x + 255) & ~(size_t)255; }

extern "C" void kernel_launch(void* const* d_in, const int* in_sizes, int n_in,
                              void* d_out, int out_size, void* d_ws, size_t ws_size,
                              hipStream_t stream) {
    const float* node_emb = (const float*)d_in[0];
    const float* adj_val  = (const float*)d_in[1];
    const int*   adj_row  = (const int*)d_in[2];
    const int*   adj_col  = (const int*)d_in[3];
    const int*   user_ids = (const int*)d_in[4];
    const int*   item_ids = (const int*)d_in[5];
    float* out = (float*)d_out;

    const int n_edges = in_sizes[1];
    const int batch   = in_sizes[4];

    const size_t emb_bytes = (size_t)N_TOTAL * DIM * sizeof(float);

    char* p = (char*)d_ws;
    size_t off = 0;
    float* bufA = (float*)(p + off); off = align256(off + emb_bytes);
    float* bufB = (float*)(p + off); off = align256(off + emb_bytes);
    float* acc  = (float*)(p + off); off = align256(off + (size_t)2 * batch * DIM * sizeof(float));
    int* row_start = (int*)(p + off); off = align256(off + (size_t)(N_TOTAL + 1) * sizeof(int));
    int* cursor    = (int*)(p + off); off = align256(off + (size_t)N_TOTAL * sizeof(int));
    int* partial   = (int*)(p + off); off = align256(off + (size_t)SCAN_NB * sizeof(int));
    int2* pair     = (int2*)(p + off); off = align256(off + (size_t)n_edges * sizeof(int2));
    (void)ws_size;

    const int eblocks = (n_edges + 255) / 256;

    // --- CSR build ---
    hipMemsetAsync(cursor, 0, (size_t)N_TOTAL * sizeof(int), stream);
    count_rows<<<eblocks, 256, 0, stream>>>(adj_row, cursor, n_edges);
    scan_block_sums<<<SCAN_NB, SCAN_TPB, 0, stream>>>(cursor, partial);
    scan_partials<<<1, 128, 0, stream>>>(partial, row_start);
    scan_write<<<SCAN_NB, SCAN_TPB, 0, stream>>>(cursor, partial, row_start);
    fill_csr<<<eblocks, 256, 0, stream>>>(adj_row, adj_col, adj_val, cursor,
                                          pair, n_edges);

    // --- acc init (layer-0) ---
    {
        int threads = 2 * batch * 16;
        gather_init<<<(threads + 255) / 256, 256, 0, stream>>>(
            (const float4*)node_emb, user_ids, item_ids, (float4*)acc, batch);
    }

    const int rblocks = ((N_TOTAL * 16) + 255) / 256;
    const int gblocks = ((2 * batch * 16) + 255) / 256;

    // layer 1: full
    spmm_csr<<<rblocks, 256, 0, stream>>>((const float4*)node_emb, row_start, pair,
                                          (float4*)bufA);
    acc_gather_add<<<gblocks, 256, 0, stream>>>((const float4*)bufA, user_ids,
                                                item_ids, (float4*)acc, batch);

    // layer 2: full
    spmm_csr<<<rblocks, 256, 0, stream>>>((const float4*)bufA, row_start, pair,
                                          (float4*)bufB);
    acc_gather_add<<<gblocks, 256, 0, stream>>>((const float4*)bufB, user_ids,
                                                item_ids, (float4*)acc, batch);

    // layer 3: only the 2*batch rows we actually read
    spmm_rows_acc<<<gblocks, 256, 0, stream>>>((const float4*)bufB, row_start, pair,
                                               user_ids, item_ids, (float4*)acc, batch);

    // readout
    {
        int threads = batch * 16;
        final_dot<<<(threads + 255) / 256, 256, 0, stream>>>((const float4*)acc, out, batch);
    }
}